// Round 13
// baseline (155.230 us; speedup 1.0000x reference)
//
#include <hip/hip_runtime.h>
#include <math.h>

#define N_NODES 20000
#define N_EDGES 320000
#define E_PAD 320032               // N_EDGES + 32, multiple of 8
#define DIM 64
#define SUB 16
#define NRBF 8
#define NB 5
#define LAYERS 3
#define FCIN (NRBF*SUB*NB + SUB)   // 656
#define KPAD 672                   // 21 * 32
#define NKK 21
#define HD 64
#define CUTOFF 5.0f
#define TS 680                     // LDS cat-tile row stride (ush): 2-way banks

typedef __attribute__((ext_vector_type(8))) short short8;
typedef __attribute__((ext_vector_type(4))) float float4v;

__device__ __forceinline__ float ssp(float x) {
    float sp = fmaxf(x, 0.0f) + log1pf(expf(-fabsf(x)));
    return sp - 0.69314718055994530942f;
}

__device__ __forceinline__ unsigned short f2bf(float x) {
    unsigned int u = __float_as_uint(x);
    unsigned int r = (u + 0x7FFFu + ((u >> 16) & 1u)) >> 16;
    return (unsigned short)r;
}

// --- one-time kernels -------------------------------------------------------

__global__ void k_rowptr(const int* __restrict__ esrc, int* __restrict__ rowptr) {
    int n = blockIdx.x * blockDim.x + threadIdx.x;
    if (n > N_NODES) return;
    int a = 0, b = N_EDGES;
    while (a < b) { int m = (a + b) >> 1; if (esrc[m] < n) a = m + 1; else b = m; }
    rowptr[n] = a;
}

// uT[p][e] = bf16( sw[e] * rb[p/5] * bo[e][p%5] ) for p<40; rows 40..47 zero.
__global__ void k_u(const float* __restrict__ dist, const float* __restrict__ sw,
                    const float* __restrict__ bo, unsigned short* __restrict__ uT) {
    int e = blockIdx.x * blockDim.x + threadIdx.x;
    if (e >= E_PAD) return;
    bool oke = e < N_EDGES;
    float d  = oke ? dist[e] : 0.0f;
    float s  = oke ? sw[e]   : 0.0f;
    float rbv[NRBF], bov[NB];
    #pragma unroll
    for (int r = 0; r < NRBF; ++r) {
        float mu = (CUTOFF / (NRBF - 1)) * (float)r;
        float z = (d - mu) * ((float)NRBF / CUTOFF);
        rbv[r] = s * expf(-0.5f * z * z);
    }
    #pragma unroll
    for (int b = 0; b < NB; ++b) bov[b] = oke ? bo[e * NB + b] : 0.0f;
    #pragma unroll
    for (int p = 0; p < 48; ++p) {
        float v = (p < 40) ? rbv[p / 5] * bov[p % 5] : 0.0f;
        uT[(size_t)p * E_PAD + e] = f2bf(v);
    }
}

// Pack weights into MFMA B-fragment order (bf16). Same layout as round 3.
__global__ void k_packw(const float* __restrict__ w0, const float* __restrict__ w1,
                        const float* __restrict__ w2,
                        short* __restrict__ w0f, short* __restrict__ w1f,
                        short* __restrict__ w2f) {
    int i = blockIdx.x * blockDim.x + threadIdx.x;
    const int SZ0 = LAYERS * NKK * 4 * 64 * 8;       // 129024
    const int SZ12 = LAYERS * 2 * 4 * 64 * 8;        // 12288
    if (i < SZ0) {
        int j = i & 7, t = i >> 3;
        int lane = t & 63; t >>= 6;
        int nf = t & 3; t >>= 2;
        int kk = t % NKK, l = t / NKK;
        int kp = kk * 32 + (lane >> 4) * 8 + j;
        int col = nf * 16 + (lane & 15);
        float v = 0.0f;
        if (kp < FCIN) {
            int orig;
            if (kp < 640) {
                int j10 = kp >> 6, rem = kp & 63, g = rem >> 4, s = rem & 15;
                int p = g + 4 * j10;
                orig = (p / 5) * 80 + s * 5 + (p - 5 * (p / 5));
            } else orig = kp;
            v = w0[((size_t)l * FCIN + orig) * HD + col];
        }
        w0f[i] = (short)f2bf(v);
        return;
    }
    i -= SZ0;
    if (i < 2 * SZ12) {
        const float* W = (i < SZ12) ? w1 : w2;
        short* Wf = (i < SZ12) ? w1f : w2f;
        int ii = (i < SZ12) ? i : i - SZ12;
        int j = ii & 7, t = ii >> 3;
        int lane = t & 63; t >>= 6;
        int nf = t & 3; t >>= 2;
        int kk = t & 1, l = t >> 1;
        int kp = kk * 32 + (lane >> 4) * 8 + j;
        int col = nf * 16 + (lane & 15);
        Wf[ii] = (short)f2bf(W[((size_t)l * HD + kp) * HD + col]);
    }
}

// Fused init: xi = W_species[species]; h(0) -> si16 + mi. 8 nodes/block.
__global__ __launch_bounds__(256) void k_init(
    const int* __restrict__ species, const float* __restrict__ Wsp,
    const float* __restrict__ Wsm, const float* __restrict__ bsm,
    float* __restrict__ xi,
    unsigned short* __restrict__ si16, unsigned short* __restrict__ mi16) {
    __shared__ float xs[8][64];
    const int nl = threadIdx.x >> 5, j = threadIdx.x & 31;
    const int n = blockIdx.x * 8 + nl;
    const int sp = species[n];
    float v0 = Wsp[sp * DIM + j];
    float v1 = Wsp[sp * DIM + 32 + j];
    xi[(size_t)n * DIM + j] = v0;
    xi[(size_t)n * DIM + 32 + j] = v1;
    xs[nl][j] = v0;
    xs[nl][32 + j] = v1;
    __syncthreads();
    float v = bsm[j];
    const float* xr = &xs[nl][0];
    #pragma unroll 8
    for (int d = 0; d < DIM; ++d) v = fmaf(xr[d], Wsm[d * 2 * SUB + j], v);
    if (j < SUB) si16[(size_t)n * SUB + j] = f2bf(v);
    else         mi16[(size_t)n * SUB + (j - SUB)] = f2bf(v);
}

// --- per-layer kernels ------------------------------------------------------

// Transposed edge gather: mT[x][e] = mi16[edst[e]][x], x = 0..15.
// Reads: edst coalesced; mi rows 32B from the 640KB L2-resident table.
// Writes: for each x, lane-consecutive e -> coalesced 128B segments.
__global__ __launch_bounds__(256) void k_gather(
    const int* __restrict__ edst,
    const unsigned short* __restrict__ mi16,
    unsigned short* __restrict__ mT) {
    int e = blockIdx.x * blockDim.x + threadIdx.x;
    if (e >= N_EDGES) return;
    int dst = edst[e];
    uint4 lo = *(const uint4*)(mi16 + (size_t)dst * 16);
    uint4 hi = *(const uint4*)(mi16 + (size_t)dst * 16 + 8);
    unsigned int vals[8] = {lo.x, lo.y, lo.z, lo.w, hi.x, hi.y, hi.z, hi.w};
    #pragma unroll
    for (int q = 0; q < 8; ++q) {
        mT[(size_t)(2 * q) * E_PAD + e]     = (unsigned short)(vals[q] & 0xFFFFu);
        mT[(size_t)(2 * q + 1) * E_PAD + e] = (unsigned short)(vals[q] >> 16);
    }
}

// --- fused per-layer kernel -------------------------------------------------
// Block = 16 nodes, 4 waves.
// Phase A: MFMA aggregation, A (uT) and B (mT) fragments both AFFINE 16B
//   streams -> compiler software-pipelines freely; only mask VALU remains.
// Phase B: fc0 (A from LDS tile) -> fc1 -> fc2 + residual -> h(l+1) epilogue.
// h1/h2/xi_s overlay the tile (dead after fc0) -> LDS = 21.8 KB only.
__global__ __launch_bounds__(256) void k_layer(
    const int* __restrict__ rowptr,
    const unsigned short* __restrict__ uT,
    const unsigned short* __restrict__ mT,
    unsigned short* __restrict__ mi16,
    unsigned short* __restrict__ si16,
    const short* __restrict__ w0f, const float* __restrict__ b0,
    const short* __restrict__ w1f, const float* __restrict__ b1,
    const short* __restrict__ w2f, const float* __restrict__ b2,
    const float* __restrict__ Wsm, const float* __restrict__ bsm,
    float* __restrict__ xi, int l)
{
    __shared__ __align__(16) unsigned short tile[16][TS];    // 21760 B total LDS
    unsigned short (*h1)[72] = (unsigned short (*)[72])((char*)tile);          // 2304 B
    unsigned short (*h2)[72] = (unsigned short (*)[72])((char*)tile + 4608);   // 2304 B
    float (*xi_s)[68]        = (float (*)[68])((char*)tile + 9216);            // 4352 B

    const int lane = threadIdx.x & 63;
    const int w = threadIdx.x >> 6;
    const int n0 = blockIdx.x * 16;
    const int x = lane & 15, g = lane >> 4;

    // ---- Phase A: MFMA aggregation into LDS tile, all-affine streams ----
    const unsigned short* mrow = mT + (size_t)x * E_PAD;
    const unsigned short* urow = uT + (size_t)x * E_PAD;
    for (int nn = 0; nn < 4; ++nn) {
        const int n = n0 + 4 * w + nn;
        const int lo = rowptr[n], hi = rowptr[n + 1];
        float4v acc0 = {0.f,0.f,0.f,0.f};
        float4v acc1 = {0.f,0.f,0.f,0.f};
        float4v acc2 = {0.f,0.f,0.f,0.f};

        for (int ba = lo & ~31; ba < hi; ba += 32) {
            short8 braw = *(const short8*)(mrow + ba + g * 8);
            const int klo = lo - ba, khi = hi - ba;
            const int kb = g * 8;
            short8 bq;
            #pragma unroll
            for (int j = 0; j < 8; ++j)
                bq[j] = (kb + j >= klo && kb + j < khi) ? braw[j] : (short)0;

            const unsigned short* ap = urow + ba + g * 8;
            short8 a0 = *(const short8*)(ap);
            short8 a1 = *(const short8*)(ap + (size_t)16 * E_PAD);
            short8 a2 = *(const short8*)(ap + (size_t)32 * E_PAD);
            acc0 = __builtin_amdgcn_mfma_f32_16x16x32_bf16(a0, bq, acc0, 0, 0, 0);
            acc1 = __builtin_amdgcn_mfma_f32_16x16x32_bf16(a1, bq, acc1, 0, 0, 0);
            acc2 = __builtin_amdgcn_mfma_f32_16x16x32_bf16(a2, bq, acc2, 0, 0, 0);
        }

        const int row = 4 * w + nn;
        unsigned short* tp = &tile[row][0];
        #pragma unroll
        for (int i = 0; i < 4; ++i) {
            int p = g * 4 + i;
            tp[(p >> 2) * 64 + (p & 3) * 16 + x] = f2bf(acc0[i]);
        }
        #pragma unroll
        for (int i = 0; i < 4; ++i) {
            int p = 16 + g * 4 + i;
            tp[(p >> 2) * 64 + (p & 3) * 16 + x] = f2bf(acc1[i]);
        }
        if (g < 2) {
            #pragma unroll
            for (int i = 0; i < 4; ++i) {
                int p = 32 + g * 4 + i;
                tp[(p >> 2) * 64 + (p & 3) * 16 + x] = f2bf(acc2[i]);
            }
        }
        if (lane < SUB)      tp[640 + lane] = si16[(size_t)n * SUB + lane];
        else if (lane < 32)  tp[640 + lane] = 0;   // pad cols 656..671
    }
    __syncthreads();

    // ---- Phase B: MFMA MLP (A-frags from LDS tile) ----
    const int r = x;
    const short* Bp = w0f + ((size_t)l * NKK * 256 + w * 64 + lane) * 8;
    float bv = b0[l * HD + w * 16 + r];
    float4v accA = {bv, bv, bv, bv};
    float4v accB = {0.f, 0.f, 0.f, 0.f};
    #pragma unroll 5
    for (int kk = 0; kk < 20; kk += 2) {
        short8 aA = *(const short8*)((const short*)&tile[r][kk * 32 + g * 8]);
        short8 bA = *(const short8*)(Bp + (size_t)kk * 2048);
        accA = __builtin_amdgcn_mfma_f32_16x16x32_bf16(aA, bA, accA, 0, 0, 0);
        short8 aB = *(const short8*)((const short*)&tile[r][(kk + 1) * 32 + g * 8]);
        short8 bB = *(const short8*)(Bp + (size_t)(kk + 1) * 2048);
        accB = __builtin_amdgcn_mfma_f32_16x16x32_bf16(aB, bB, accB, 0, 0, 0);
    }
    {
        short8 a = *(const short8*)((const short*)&tile[r][20 * 32 + g * 8]);
        short8 b = *(const short8*)(Bp + (size_t)20 * 2048);
        accA = __builtin_amdgcn_mfma_f32_16x16x32_bf16(a, b, accA, 0, 0, 0);
    }
    __syncthreads();   // all tile reads done before h1 overlays it
    #pragma unroll
    for (int i = 0; i < 4; ++i)
        h1[g * 4 + i][w * 16 + r] = f2bf(ssp(accA[i] + accB[i]));
    __syncthreads();

    // fc1
    bv = b1[l * HD + w * 16 + r];
    float4v acc1v = {bv, bv, bv, bv};
    #pragma unroll
    for (int kk = 0; kk < 2; ++kk) {
        short8 a = *(const short8*)((const short*)&h1[r][kk * 32 + g * 8]);
        short8 b = *(const short8*)(w1f + ((size_t)(l * 2 + kk) * 256 + w * 64 + lane) * 8);
        acc1v = __builtin_amdgcn_mfma_f32_16x16x32_bf16(a, b, acc1v, 0, 0, 0);
    }
    #pragma unroll
    for (int i = 0; i < 4; ++i)
        h2[g * 4 + i][w * 16 + r] = f2bf(ssp(acc1v[i]));   // h2 disjoint from h1
    __syncthreads();

    // fc2 + residual; stage fresh xi rows for the h epilogue
    bv = b2[l * DIM + w * 16 + r];
    float4v acc2v = {bv, bv, bv, bv};
    #pragma unroll
    for (int kk = 0; kk < 2; ++kk) {
        short8 a = *(const short8*)((const short*)&h2[r][kk * 32 + g * 8]);
        short8 b = *(const short8*)(w2f + ((size_t)(l * 2 + kk) * 256 + w * 64 + lane) * 8);
        acc2v = __builtin_amdgcn_mfma_f32_16x16x32_bf16(a, b, acc2v, 0, 0, 0);
    }
    #pragma unroll
    for (int i = 0; i < 4; ++i) {
        size_t idx = (size_t)(n0 + g * 4 + i) * DIM + w * 16 + r;
        float nv = xi[idx] + acc2v[i];
        xi[idx] = nv;
        xi_s[g * 4 + i][w * 16 + r] = nv;   // xi_s disjoint from h2
    }

    // h(l+1) epilogue: exact fp32 (same math as k_init's h).
    // mi16 is safe to overwrite: this layer's consumer (k_gather) already ran.
    if (l + 1 < LAYERS) {
        __syncthreads();
        const float* W  = Wsm + (size_t)(l + 1) * DIM * 2 * SUB;
        const float* bs = bsm + (l + 1) * 2 * SUB;
        #pragma unroll
        for (int pp = 0; pp < 2; ++pp) {
            int pair = threadIdx.x + pp * 256;
            int nl = pair >> 5, j = pair & 31;
            float v = bs[j];
            const float* xr = &xi_s[nl][0];
            #pragma unroll 8
            for (int d = 0; d < DIM; ++d) v = fmaf(xr[d], W[d * 2 * SUB + j], v);
            int n = n0 + nl;
            if (j < SUB) si16[(size_t)n * SUB + j] = f2bf(v);
            else         mi16[(size_t)n * SUB + (j - SUB)] = f2bf(v);
        }
    }
}

extern "C" void kernel_launch(void* const* d_in, const int* in_sizes, int n_in,
                              void* d_out, int out_size, void* d_ws, size_t ws_size,
                              hipStream_t stream) {
    const int*   species = (const int*)  d_in[0];
    const int*   esrc    = (const int*)  d_in[1];
    const int*   edst    = (const int*)  d_in[2];
    const float* dist    = (const float*)d_in[3];
    const float* sw      = (const float*)d_in[4];
    const float* bo      = (const float*)d_in[5];
    const float* Wsp     = (const float*)d_in[6];
    const float* Wsm     = (const float*)d_in[7];
    const float* bsm     = (const float*)d_in[8];
    const float* w0      = (const float*)d_in[9];
    const float* b0      = (const float*)d_in[10];
    const float* w1      = (const float*)d_in[11];
    const float* b1      = (const float*)d_in[12];
    const float* w2      = (const float*)d_in[13];
    const float* b2      = (const float*)d_in[14];

    float* xi = (float*)d_out;   // N x 64 fp32, updated in place

    // ws layout: uT 48*E_PAD ush | mT 16*E_PAD ush | mi16 N*16 ush |
    //            si16 N*16 ush | w0f | w1f | w2f | rowptr
    unsigned short* uT    = (unsigned short*)d_ws;
    unsigned short* mT    = uT + (size_t)48 * E_PAD;
    unsigned short* mi16  = mT + (size_t)16 * E_PAD;
    unsigned short* si16  = mi16 + (size_t)N_NODES * SUB;
    short* w0f = (short*)(si16 + (size_t)N_NODES * SUB);
    short* w1f = w0f + (size_t)LAYERS * NKK * 2048;
    short* w2f = w1f + (size_t)LAYERS * 2 * 2048;
    int* rowptr = (int*)(w2f + (size_t)LAYERS * 2 * 2048);

    k_rowptr<<<(N_NODES + 1 + 255) / 256, 256, 0, stream>>>(esrc, rowptr);
    k_u<<<(E_PAD + 255) / 256, 256, 0, stream>>>(dist, sw, bo, uT);
    {
        int total = LAYERS * NKK * 2048 + 2 * LAYERS * 2 * 2048;
        k_packw<<<(total + 255) / 256, 256, 0, stream>>>(w0, w1, w2, w0f, w1f, w2f);
    }
    k_init<<<N_NODES / 8, 256, 0, stream>>>(species, Wsp, Wsm, bsm, xi, si16, mi16);

    for (int l = 0; l < LAYERS; ++l) {
        k_gather<<<(N_EDGES + 255) / 256, 256, 0, stream>>>(edst, mi16, mT);
        k_layer<<<N_NODES / 16, 256, 0, stream>>>(rowptr, uT, mT, mi16,
                                                  si16, w0f, b0, w1f, b1, w2f, b2,
                                                  Wsm, bsm, xi, l);
    }
}

// Round 14
// 117.706 us; speedup vs baseline: 1.3188x; 1.3188x over previous
//
#include <hip/hip_runtime.h>
#include <math.h>

#define N_NODES 20000
#define N_EDGES 320000
#define E_PAD 320032               // N_EDGES + 32, multiple of 8
#define DIM 64
#define SUB 16
#define NRBF 8
#define NB 5
#define LAYERS 3
#define FCIN (NRBF*SUB*NB + SUB)   // 656
#define KPAD 672                   // 21 * 32
#define NKK 21
#define HD 64
#define CUTOFF 5.0f
#define TS 680                     // LDS cat-tile row stride (ush): 2-way banks

typedef __attribute__((ext_vector_type(8))) short short8;
typedef __attribute__((ext_vector_type(4))) float float4v;

__device__ __forceinline__ float ssp(float x) {
    float sp = fmaxf(x, 0.0f) + log1pf(expf(-fabsf(x)));
    return sp - 0.69314718055994530942f;
}

__device__ __forceinline__ unsigned short f2bf(float x) {
    unsigned int u = __float_as_uint(x);
    unsigned int r = (u + 0x7FFFu + ((u >> 16) & 1u)) >> 16;
    return (unsigned short)r;
}

// --- one-time kernels -------------------------------------------------------

// Merged: blocks [0,79) -> rowptr binary search; blocks [79,...) -> weight pack.
__global__ void k_prep(const int* __restrict__ esrc, int* __restrict__ rowptr,
                       const float* __restrict__ w0, const float* __restrict__ w1,
                       const float* __restrict__ w2,
                       short* __restrict__ w0f, short* __restrict__ w1f,
                       short* __restrict__ w2f) {
    const int SZ0 = LAYERS * NKK * 4 * 64 * 8;       // 129024
    const int SZ12 = LAYERS * 2 * 4 * 64 * 8;        // 12288
    if (blockIdx.x < 79) {
        int n = blockIdx.x * 256 + threadIdx.x;
        if (n > N_NODES) return;
        int a = 0, b = N_EDGES;
        while (a < b) { int m = (a + b) >> 1; if (esrc[m] < n) a = m + 1; else b = m; }
        rowptr[n] = a;
        return;
    }
    int i = (blockIdx.x - 79) * 256 + threadIdx.x;
    if (i < SZ0) {
        int j = i & 7, t = i >> 3;
        int lane = t & 63; t >>= 6;
        int nf = t & 3; t >>= 2;
        int kk = t % NKK, l = t / NKK;
        int kp = kk * 32 + (lane >> 4) * 8 + j;
        int col = nf * 16 + (lane & 15);
        float v = 0.0f;
        if (kp < FCIN) {
            int orig;
            if (kp < 640) {
                int j10 = kp >> 6, rem = kp & 63, g = rem >> 4, s = rem & 15;
                int p = g + 4 * j10;
                orig = (p / 5) * 80 + s * 5 + (p - 5 * (p / 5));
            } else orig = kp;
            v = w0[((size_t)l * FCIN + orig) * HD + col];
        }
        w0f[i] = (short)f2bf(v);
        return;
    }
    i -= SZ0;
    if (i < 2 * SZ12) {
        const float* W = (i < SZ12) ? w1 : w2;
        short* Wf = (i < SZ12) ? w1f : w2f;
        int ii = (i < SZ12) ? i : i - SZ12;
        int j = ii & 7, t = ii >> 3;
        int lane = t & 63; t >>= 6;
        int nf = t & 3; t >>= 2;
        int kk = t & 1, l = t >> 1;
        int kp = kk * 32 + (lane >> 4) * 8 + j;
        int col = nf * 16 + (lane & 15);
        Wf[ii] = (short)f2bf(W[((size_t)l * HD + kp) * HD + col]);
    }
}

// uT[p][e] = bf16( sw[e] * rb[p/5] * bo[e][p%5] ) for p<40; rows 40..47 zero.
__global__ void k_u(const float* __restrict__ dist, const float* __restrict__ sw,
                    const float* __restrict__ bo, unsigned short* __restrict__ uT) {
    int e = blockIdx.x * blockDim.x + threadIdx.x;
    if (e >= E_PAD) return;
    bool oke = e < N_EDGES;
    float d  = oke ? dist[e] : 0.0f;
    float s  = oke ? sw[e]   : 0.0f;
    float rbv[NRBF], bov[NB];
    #pragma unroll
    for (int r = 0; r < NRBF; ++r) {
        float mu = (CUTOFF / (NRBF - 1)) * (float)r;
        float z = (d - mu) * ((float)NRBF / CUTOFF);
        rbv[r] = s * expf(-0.5f * z * z);
    }
    #pragma unroll
    for (int b = 0; b < NB; ++b) bov[b] = oke ? bo[e * NB + b] : 0.0f;
    #pragma unroll
    for (int p = 0; p < 48; ++p) {
        float v = (p < 40) ? rbv[p / 5] * bov[p % 5] : 0.0f;
        uT[(size_t)p * E_PAD + e] = f2bf(v);
    }
}

// Fused init: xi = W_species[species]; h(0) -> si16 + mi. 8 nodes/block.
__global__ __launch_bounds__(256) void k_init(
    const int* __restrict__ species, const float* __restrict__ Wsp,
    const float* __restrict__ Wsm, const float* __restrict__ bsm,
    float* __restrict__ xi,
    unsigned short* __restrict__ si16, unsigned short* __restrict__ mi16) {
    __shared__ float xs[8][64];
    const int nl = threadIdx.x >> 5, j = threadIdx.x & 31;
    const int n = blockIdx.x * 8 + nl;
    const int sp = species[n];
    float v0 = Wsp[sp * DIM + j];
    float v1 = Wsp[sp * DIM + 32 + j];
    xi[(size_t)n * DIM + j] = v0;
    xi[(size_t)n * DIM + 32 + j] = v1;
    xs[nl][j] = v0;
    xs[nl][32 + j] = v1;
    __syncthreads();
    float v = bsm[j];
    const float* xr = &xs[nl][0];
    #pragma unroll 8
    for (int d = 0; d < DIM; ++d) v = fmaf(xr[d], Wsm[d * 2 * SUB + j], v);
    if (j < SUB) si16[(size_t)n * SUB + j] = f2bf(v);
    else         mi16[(size_t)n * SUB + (j - SUB)] = f2bf(v);
}

// --- fused per-layer kernel -------------------------------------------------
// Block = 16 nodes, 4 waves.
// Phase A: UNION-SWEEP MFMA aggregation — wave w sweeps the contiguous edge
//   range of its 4 nodes ONCE; each chunk's A-frags/edst/mi-gathers loaded
//   once, then per overlapping node (wave-uniform branch) mask + MFMA.
//   Chunk grid is 32-aligned exactly as before -> bitwise-identical results.
// Phase B: fc0 (A from LDS tile) -> fc1 -> fc2 + residual -> h(l+1) epilogue.
__global__ __launch_bounds__(256) void k_layer(
    const int* __restrict__ rowptr, const int* __restrict__ edst,
    const unsigned short* __restrict__ uT,
    const unsigned short* __restrict__ mi_rd,
    unsigned short* __restrict__ mi_wr,
    unsigned short* __restrict__ si16,
    const short* __restrict__ w0f, const float* __restrict__ b0,
    const short* __restrict__ w1f, const float* __restrict__ b1,
    const short* __restrict__ w2f, const float* __restrict__ b2,
    const float* __restrict__ Wsm, const float* __restrict__ bsm,
    float* __restrict__ xi, int l)
{
    __shared__ __align__(16) unsigned short tile[16][TS];    // 21760 B total LDS
    unsigned short (*h1)[72] = (unsigned short (*)[72])((char*)tile);          // 2304 B
    unsigned short (*h2)[72] = (unsigned short (*)[72])((char*)tile + 4608);   // 2304 B
    float (*xi_s)[68]        = (float (*)[68])((char*)tile + 9216);            // 4352 B

    const int lane = threadIdx.x & 63;
    const int w = threadIdx.x >> 6;
    const int n0 = blockIdx.x * 16;
    const int x = lane & 15, g = lane >> 4;

    // ---- Phase A: union-sweep MFMA aggregation into LDS tile ----
    const unsigned short* mx = mi_rd + x;
    const unsigned short* urow = uT + (size_t)x * E_PAD;
    const int base = n0 + 4 * w;
    int rp[5];
    #pragma unroll
    for (int i = 0; i < 5; ++i) rp[i] = rowptr[base + i];

    float4v a00={0,0,0,0}, a01={0,0,0,0}, a02={0,0,0,0};
    float4v a10={0,0,0,0}, a11={0,0,0,0}, a12={0,0,0,0};
    float4v a20={0,0,0,0}, a21={0,0,0,0}, a22={0,0,0,0};
    float4v a30={0,0,0,0}, a31={0,0,0,0}, a32={0,0,0,0};

    const int kb = g * 8;
    for (int ba = rp[0] & ~31; ba < rp[4]; ba += 32) {
        // shared loads for this chunk (once per chunk, all 4 nodes)
        int4 i0 = *(const int4*)(edst + ba + kb);
        int4 i1 = *(const int4*)(edst + ba + kb + 4);
        // clamp (as unsigned) so tail-garbage indices stay in-bounds; values masked later
        unsigned c0 = min((unsigned)i0.x, (unsigned)(N_NODES - 1));
        unsigned c1 = min((unsigned)i0.y, (unsigned)(N_NODES - 1));
        unsigned c2 = min((unsigned)i0.z, (unsigned)(N_NODES - 1));
        unsigned c3 = min((unsigned)i0.w, (unsigned)(N_NODES - 1));
        unsigned c4 = min((unsigned)i1.x, (unsigned)(N_NODES - 1));
        unsigned c5 = min((unsigned)i1.y, (unsigned)(N_NODES - 1));
        unsigned c6 = min((unsigned)i1.z, (unsigned)(N_NODES - 1));
        unsigned c7 = min((unsigned)i1.w, (unsigned)(N_NODES - 1));
        short8 braw;
        braw[0] = (short)mx[(size_t)c0 * 16];
        braw[1] = (short)mx[(size_t)c1 * 16];
        braw[2] = (short)mx[(size_t)c2 * 16];
        braw[3] = (short)mx[(size_t)c3 * 16];
        braw[4] = (short)mx[(size_t)c4 * 16];
        braw[5] = (short)mx[(size_t)c5 * 16];
        braw[6] = (short)mx[(size_t)c6 * 16];
        braw[7] = (short)mx[(size_t)c7 * 16];

        const unsigned short* ap = urow + ba + kb;
        short8 f0 = *(const short8*)(ap);
        short8 f1 = *(const short8*)(ap + (size_t)16 * E_PAD);
        short8 f2 = *(const short8*)(ap + (size_t)32 * E_PAD);

        // per-node masked MFMA (wave-uniform branches)
        #define NODE_STEP(ND, A0, A1, A2)                                     \
        if (ba < rp[ND + 1] && ba + 32 > rp[ND]) {                            \
            const int klo = rp[ND] - ba, khi = rp[ND + 1] - ba;               \
            short8 bq;                                                        \
            if (klo <= 0 && khi >= 32) {                                      \
                bq = braw;                                                    \
            } else {                                                          \
                _Pragma("unroll")                                             \
                for (int j = 0; j < 8; ++j)                                   \
                    bq[j] = (kb + j >= klo && kb + j < khi) ? braw[j] : (short)0; \
            }                                                                 \
            A0 = __builtin_amdgcn_mfma_f32_16x16x32_bf16(f0, bq, A0, 0, 0, 0);\
            A1 = __builtin_amdgcn_mfma_f32_16x16x32_bf16(f1, bq, A1, 0, 0, 0);\
            A2 = __builtin_amdgcn_mfma_f32_16x16x32_bf16(f2, bq, A2, 0, 0, 0);\
        }
        NODE_STEP(0, a00, a01, a02)
        NODE_STEP(1, a10, a11, a12)
        NODE_STEP(2, a20, a21, a22)
        NODE_STEP(3, a30, a31, a32)
        #undef NODE_STEP
    }

    // C-writes: node nd -> tile row 4w+nd; kp = (p>>2)*64 + (p&3)*16 + x
    #define NODE_STORE(ND, A0, A1, A2)                                        \
    {                                                                         \
        unsigned short* tp = &tile[4 * w + ND][0];                            \
        _Pragma("unroll")                                                     \
        for (int i = 0; i < 4; ++i) {                                         \
            int p = g * 4 + i;                                                \
            tp[(p >> 2) * 64 + (p & 3) * 16 + x] = f2bf(A0[i]);               \
        }                                                                     \
        _Pragma("unroll")                                                     \
        for (int i = 0; i < 4; ++i) {                                         \
            int p = 16 + g * 4 + i;                                           \
            tp[(p >> 2) * 64 + (p & 3) * 16 + x] = f2bf(A1[i]);               \
        }                                                                     \
        if (g < 2) {                                                          \
            _Pragma("unroll")                                                 \
            for (int i = 0; i < 4; ++i) {                                     \
                int p = 32 + g * 4 + i;                                       \
                tp[(p >> 2) * 64 + (p & 3) * 16 + x] = f2bf(A2[i]);           \
            }                                                                 \
        }                                                                     \
        if (lane < SUB)      tp[640 + lane] = si16[(size_t)(base + ND) * SUB + lane]; \
        else if (lane < 32)  tp[640 + lane] = 0;                              \
    }
    NODE_STORE(0, a00, a01, a02)
    NODE_STORE(1, a10, a11, a12)
    NODE_STORE(2, a20, a21, a22)
    NODE_STORE(3, a30, a31, a32)
    #undef NODE_STORE
    __syncthreads();

    // ---- Phase B: MFMA MLP (A-frags from LDS tile) ----
    const int r = x;
    const short* Bp = w0f + ((size_t)l * NKK * 256 + w * 64 + lane) * 8;
    float bv = b0[l * HD + w * 16 + r];
    float4v accA = {bv, bv, bv, bv};
    float4v accB = {0.f, 0.f, 0.f, 0.f};
    #pragma unroll 5
    for (int kk = 0; kk < 20; kk += 2) {
        short8 aA = *(const short8*)((const short*)&tile[r][kk * 32 + g * 8]);
        short8 bA = *(const short8*)(Bp + (size_t)kk * 2048);
        accA = __builtin_amdgcn_mfma_f32_16x16x32_bf16(aA, bA, accA, 0, 0, 0);
        short8 aB = *(const short8*)((const short*)&tile[r][(kk + 1) * 32 + g * 8]);
        short8 bB = *(const short8*)(Bp + (size_t)(kk + 1) * 2048);
        accB = __builtin_amdgcn_mfma_f32_16x16x32_bf16(aB, bB, accB, 0, 0, 0);
    }
    {
        short8 a = *(const short8*)((const short*)&tile[r][20 * 32 + g * 8]);
        short8 b = *(const short8*)(Bp + (size_t)20 * 2048);
        accA = __builtin_amdgcn_mfma_f32_16x16x32_bf16(a, b, accA, 0, 0, 0);
    }
    __syncthreads();   // all tile reads done before h1 overlays it
    #pragma unroll
    for (int i = 0; i < 4; ++i)
        h1[g * 4 + i][w * 16 + r] = f2bf(ssp(accA[i] + accB[i]));
    __syncthreads();

    // fc1
    bv = b1[l * HD + w * 16 + r];
    float4v acc1v = {bv, bv, bv, bv};
    #pragma unroll
    for (int kk = 0; kk < 2; ++kk) {
        short8 a = *(const short8*)((const short*)&h1[r][kk * 32 + g * 8]);
        short8 b = *(const short8*)(w1f + ((size_t)(l * 2 + kk) * 256 + w * 64 + lane) * 8);
        acc1v = __builtin_amdgcn_mfma_f32_16x16x32_bf16(a, b, acc1v, 0, 0, 0);
    }
    #pragma unroll
    for (int i = 0; i < 4; ++i)
        h2[g * 4 + i][w * 16 + r] = f2bf(ssp(acc1v[i]));   // h2 disjoint from h1
    __syncthreads();

    // fc2 + residual; stage fresh xi rows for the h epilogue
    bv = b2[l * DIM + w * 16 + r];
    float4v acc2v = {bv, bv, bv, bv};
    #pragma unroll
    for (int kk = 0; kk < 2; ++kk) {
        short8 a = *(const short8*)((const short*)&h2[r][kk * 32 + g * 8]);
        short8 b = *(const short8*)(w2f + ((size_t)(l * 2 + kk) * 256 + w * 64 + lane) * 8);
        acc2v = __builtin_amdgcn_mfma_f32_16x16x32_bf16(a, b, acc2v, 0, 0, 0);
    }
    #pragma unroll
    for (int i = 0; i < 4; ++i) {
        size_t idx = (size_t)(n0 + g * 4 + i) * DIM + w * 16 + r;
        float nv = xi[idx] + acc2v[i];
        xi[idx] = nv;
        xi_s[g * 4 + i][w * 16 + r] = nv;   // xi_s disjoint from h2
    }

    // h(l+1) epilogue: exact fp32 (same math as k_init's h)
    if (l + 1 < LAYERS) {
        __syncthreads();
        const float* W  = Wsm + (size_t)(l + 1) * DIM * 2 * SUB;
        const float* bs = bsm + (l + 1) * 2 * SUB;
        #pragma unroll
        for (int pp = 0; pp < 2; ++pp) {
            int pair = threadIdx.x + pp * 256;
            int nl = pair >> 5, j = pair & 31;
            float v = bs[j];
            const float* xr = &xi_s[nl][0];
            #pragma unroll 8
            for (int d = 0; d < DIM; ++d) v = fmaf(xr[d], W[d * 2 * SUB + j], v);
            int n = n0 + nl;
            if (j < SUB) si16[(size_t)n * SUB + j] = f2bf(v);
            else         mi_wr[(size_t)n * SUB + (j - SUB)] = f2bf(v);
        }
    }
}

extern "C" void kernel_launch(void* const* d_in, const int* in_sizes, int n_in,
                              void* d_out, int out_size, void* d_ws, size_t ws_size,
                              hipStream_t stream) {
    const int*   species = (const int*)  d_in[0];
    const int*   esrc    = (const int*)  d_in[1];
    const int*   edst    = (const int*)  d_in[2];
    const float* dist    = (const float*)d_in[3];
    const float* sw      = (const float*)d_in[4];
    const float* bo      = (const float*)d_in[5];
    const float* Wsp     = (const float*)d_in[6];
    const float* Wsm     = (const float*)d_in[7];
    const float* bsm     = (const float*)d_in[8];
    const float* w0      = (const float*)d_in[9];
    const float* b0      = (const float*)d_in[10];
    const float* w1      = (const float*)d_in[11];
    const float* b1      = (const float*)d_in[12];
    const float* w2      = (const float*)d_in[13];
    const float* b2      = (const float*)d_in[14];

    float* xi = (float*)d_out;   // N x 64 fp32, updated in place

    // ws layout: uT 48*E_PAD ush | mi16 2 x N*16 ush | si16 N*16 ush |
    //            w0f | w1f | w2f | rowptr
    unsigned short* uT    = (unsigned short*)d_ws;
    unsigned short* mi0   = uT + (size_t)48 * E_PAD;
    unsigned short* mi1   = mi0 + (size_t)N_NODES * SUB;
    unsigned short* si16  = mi1 + (size_t)N_NODES * SUB;
    short* w0f = (short*)(si16 + (size_t)N_NODES * SUB);
    short* w1f = w0f + (size_t)LAYERS * NKK * 2048;
    short* w2f = w1f + (size_t)LAYERS * 2 * 2048;
    int* rowptr = (int*)(w2f + (size_t)LAYERS * 2 * 2048);

    {
        const int SZ0 = LAYERS * NKK * 4 * 64 * 8;
        const int SZ12 = LAYERS * 2 * 4 * 64 * 8;
        int packw_blocks = (SZ0 + 2 * SZ12 + 255) / 256;   // 555
        k_prep<<<79 + packw_blocks, 256, 0, stream>>>(esrc, rowptr,
                                                      w0, w1, w2, w0f, w1f, w2f);
    }
    k_u<<<(E_PAD + 255) / 256, 256, 0, stream>>>(dist, sw, bo, uT);
    k_init<<<N_NODES / 8, 256, 0, stream>>>(species, Wsp, Wsm, bsm, xi, si16, mi0);

    for (int l = 0; l < LAYERS; ++l) {
        unsigned short* mi_rd = (l & 1) ? mi1 : mi0;
        unsigned short* mi_wr = (l & 1) ? mi0 : mi1;
        k_layer<<<N_NODES / 16, 256, 0, stream>>>(rowptr, edst, uT, mi_rd, mi_wr,
                                                  si16, w0f, b0, w1f, b1, w2f, b2,
                                                  Wsm, bsm, xi, l);
    }
}

// Round 15
// 97.539 us; speedup vs baseline: 1.5915x; 1.2068x over previous
//
#include <hip/hip_runtime.h>
#include <math.h>

#define N_NODES 20000
#define N_EDGES 320000
#define E_PAD 320032               // N_EDGES + 32, multiple of 8
#define DIM 64
#define SUB 16
#define NRBF 8
#define NB 5
#define LAYERS 3
#define FCIN (NRBF*SUB*NB + SUB)   // 656
#define KPAD 672                   // 21 * 32
#define NKK 21
#define HD 64
#define CUTOFF 5.0f
#define TS 680                     // LDS cat-tile row stride (ush): 2-way banks

// k_setup block-range sizes
#define B_ROWPTR 79                // ceil(20001/256)
#define B_PACKW  600               // (129024 + 24576) / 256
#define B_PACKSM 24                // 6144 / 256
#define B_U      1251              // ceil(E_PAD/256)
#define B_INIT   2500              // N_NODES / 8

typedef __attribute__((ext_vector_type(8))) short short8;
typedef __attribute__((ext_vector_type(4))) float float4v;

__device__ __forceinline__ float ssp(float x) {
    float sp = fmaxf(x, 0.0f) + log1pf(expf(-fabsf(x)));
    return sp - 0.69314718055994530942f;
}

__device__ __forceinline__ unsigned short f2bf(float x) {
    unsigned int u = __float_as_uint(x);
    unsigned int r = (u + 0x7FFFu + ((u >> 16) & 1u)) >> 16;
    return (unsigned short)r;
}

// --- single setup kernel: rowptr | packw | pack Wsm | uT | init ------------
__global__ __launch_bounds__(256) void k_setup(
    const int* __restrict__ esrc, int* __restrict__ rowptr,
    const float* __restrict__ w0, const float* __restrict__ w1,
    const float* __restrict__ w2,
    short* __restrict__ w0f, short* __restrict__ w1f, short* __restrict__ w2f,
    const float* __restrict__ Wsm, short* __restrict__ wsmf,
    const float* __restrict__ dist, const float* __restrict__ sw,
    const float* __restrict__ bo, unsigned short* __restrict__ uT,
    const int* __restrict__ species, const float* __restrict__ Wsp,
    const float* __restrict__ bsm, float* __restrict__ xi,
    unsigned short* __restrict__ si16, unsigned short* __restrict__ mi16)
{
    __shared__ float xs[8][64];
    const unsigned bid = blockIdx.x;

    if (bid < B_ROWPTR) {                       // ---- rowptr ----
        int n = bid * 256 + threadIdx.x;
        if (n > N_NODES) return;
        int a = 0, b = N_EDGES;
        while (a < b) { int m = (a + b) >> 1; if (esrc[m] < n) a = m + 1; else b = m; }
        rowptr[n] = a;
        return;
    }
    if (bid < B_ROWPTR + B_PACKW) {             // ---- pack w0/w1/w2 ----
        const int SZ0 = LAYERS * NKK * 4 * 64 * 8;
        const int SZ12 = LAYERS * 2 * 4 * 64 * 8;
        int i = (bid - B_ROWPTR) * 256 + threadIdx.x;
        if (i < SZ0) {
            int j = i & 7, t = i >> 3;
            int lane = t & 63; t >>= 6;
            int nf = t & 3; t >>= 2;
            int kk = t % NKK, l = t / NKK;
            int kp = kk * 32 + (lane >> 4) * 8 + j;
            int col = nf * 16 + (lane & 15);
            float v = 0.0f;
            if (kp < FCIN) {
                int orig;
                if (kp < 640) {
                    int j10 = kp >> 6, rem = kp & 63, g = rem >> 4, s = rem & 15;
                    int p = g + 4 * j10;
                    orig = (p / 5) * 80 + s * 5 + (p - 5 * (p / 5));
                } else orig = kp;
                v = w0[((size_t)l * FCIN + orig) * HD + col];
            }
            w0f[i] = (short)f2bf(v);
            return;
        }
        i -= SZ0;
        if (i < 2 * SZ12) {
            const float* W = (i < SZ12) ? w1 : w2;
            short* Wf = (i < SZ12) ? w1f : w2f;
            int ii = (i < SZ12) ? i : i - SZ12;
            int j = ii & 7, t = ii >> 3;
            int lane = t & 63; t >>= 6;
            int nf = t & 3; t >>= 2;
            int kk = t & 1, l = t >> 1;
            int kp = kk * 32 + (lane >> 4) * 8 + j;
            int col = nf * 16 + (lane & 15);
            Wf[ii] = (short)f2bf(W[((size_t)l * HD + kp) * HD + col]);
        }
        return;
    }
    if (bid < B_ROWPTR + B_PACKW + B_PACKSM) {  // ---- pack Wsm for h-GEMM ----
        // wsmf[l][kk][nf][lane][j]; kp = kk*32+(lane>>4)*8+j; col = nf*16+(lane&15)
        int i = (bid - B_ROWPTR - B_PACKW) * 256 + threadIdx.x;   // < 6144
        int j = i & 7, t = i >> 3;
        int lane = t & 63; t >>= 6;
        int nf = t & 1; t >>= 1;
        int kk = t & 1, l = t >> 1;
        int kp = kk * 32 + (lane >> 4) * 8 + j;
        int col = nf * 16 + (lane & 15);
        wsmf[i] = (short)f2bf(Wsm[(size_t)l * DIM * 2 * SUB + kp * 2 * SUB + col]);
        return;
    }
    if (bid < B_ROWPTR + B_PACKW + B_PACKSM + B_U) {   // ---- uT ----
        int e = (bid - B_ROWPTR - B_PACKW - B_PACKSM) * 256 + threadIdx.x;
        if (e >= E_PAD) return;
        bool oke = e < N_EDGES;
        float d = oke ? dist[e] : 0.0f;
        float s = oke ? sw[e] : 0.0f;
        float rbv[NRBF], bov[NB];
        #pragma unroll
        for (int r = 0; r < NRBF; ++r) {
            float mu = (CUTOFF / (NRBF - 1)) * (float)r;
            float z = (d - mu) * ((float)NRBF / CUTOFF);
            rbv[r] = s * expf(-0.5f * z * z);
        }
        #pragma unroll
        for (int b = 0; b < NB; ++b) bov[b] = oke ? bo[e * NB + b] : 0.0f;
        #pragma unroll
        for (int p = 0; p < 48; ++p) {
            float v = (p < 40) ? rbv[p / 5] * bov[p % 5] : 0.0f;
            uT[(size_t)p * E_PAD + e] = f2bf(v);
        }
        return;
    }
    {                                            // ---- init xi + h(0) ----
        int blk = bid - (B_ROWPTR + B_PACKW + B_PACKSM + B_U);
        const int nl = threadIdx.x >> 5, j = threadIdx.x & 31;
        const int n = blk * 8 + nl;
        const int sp = species[n];
        float v0 = Wsp[sp * DIM + j];
        float v1 = Wsp[sp * DIM + 32 + j];
        xi[(size_t)n * DIM + j] = v0;
        xi[(size_t)n * DIM + 32 + j] = v1;
        xs[nl][j] = v0;
        xs[nl][32 + j] = v1;
        __syncthreads();
        float v = bsm[j];
        const float* xr = &xs[nl][0];
        #pragma unroll 8
        for (int d = 0; d < DIM; ++d) v = fmaf(xr[d], Wsm[d * 2 * SUB + j], v);
        if (j < SUB) si16[(size_t)n * SUB + j] = f2bf(v);
        else         mi16[(size_t)n * SUB + (j - SUB)] = f2bf(v);
    }
}

// --- fused per-layer kernel -------------------------------------------------
// Block = 16 nodes, 4 waves.
// Phase A: union-sweep MFMA aggregation (round 14).
// Phase B: fc0 (A from LDS tile) -> fc1 -> fc2 + residual -> MFMA h-epilogue.
__global__ __launch_bounds__(256) void k_layer(
    const int* __restrict__ rowptr, const int* __restrict__ edst,
    const unsigned short* __restrict__ uT,
    const unsigned short* __restrict__ mi_rd,
    unsigned short* __restrict__ mi_wr,
    unsigned short* __restrict__ si16,
    const short* __restrict__ w0f, const float* __restrict__ b0,
    const short* __restrict__ w1f, const float* __restrict__ b1,
    const short* __restrict__ w2f, const float* __restrict__ b2,
    const short* __restrict__ wsmf, const float* __restrict__ bsm,
    float* __restrict__ xi, int l)
{
    __shared__ __align__(16) unsigned short tile[16][TS];    // 21760 B total LDS
    unsigned short (*h1)[72] = (unsigned short (*)[72])((char*)tile);          // 2304 B
    unsigned short (*h2)[72] = (unsigned short (*)[72])((char*)tile + 4608);   // 2304 B
    float (*xi_s)[68]        = (float (*)[68])((char*)tile + 9216);            // 4352 B

    const int lane = threadIdx.x & 63;
    const int w = threadIdx.x >> 6;
    const int n0 = blockIdx.x * 16;
    const int x = lane & 15, g = lane >> 4;

    // ---- Phase A: union-sweep MFMA aggregation into LDS tile ----
    const unsigned short* mx = mi_rd + x;
    const unsigned short* urow = uT + (size_t)x * E_PAD;
    const int base = n0 + 4 * w;
    int rp[5];
    #pragma unroll
    for (int i = 0; i < 5; ++i) rp[i] = rowptr[base + i];

    float4v a00={0,0,0,0}, a01={0,0,0,0}, a02={0,0,0,0};
    float4v a10={0,0,0,0}, a11={0,0,0,0}, a12={0,0,0,0};
    float4v a20={0,0,0,0}, a21={0,0,0,0}, a22={0,0,0,0};
    float4v a30={0,0,0,0}, a31={0,0,0,0}, a32={0,0,0,0};

    const int kb = g * 8;
    for (int ba = rp[0] & ~31; ba < rp[4]; ba += 32) {
        int4 i0 = *(const int4*)(edst + ba + kb);
        int4 i1 = *(const int4*)(edst + ba + kb + 4);
        unsigned c0 = min((unsigned)i0.x, (unsigned)(N_NODES - 1));
        unsigned c1 = min((unsigned)i0.y, (unsigned)(N_NODES - 1));
        unsigned c2 = min((unsigned)i0.z, (unsigned)(N_NODES - 1));
        unsigned c3 = min((unsigned)i0.w, (unsigned)(N_NODES - 1));
        unsigned c4 = min((unsigned)i1.x, (unsigned)(N_NODES - 1));
        unsigned c5 = min((unsigned)i1.y, (unsigned)(N_NODES - 1));
        unsigned c6 = min((unsigned)i1.z, (unsigned)(N_NODES - 1));
        unsigned c7 = min((unsigned)i1.w, (unsigned)(N_NODES - 1));
        short8 braw;
        braw[0] = (short)mx[(size_t)c0 * 16];
        braw[1] = (short)mx[(size_t)c1 * 16];
        braw[2] = (short)mx[(size_t)c2 * 16];
        braw[3] = (short)mx[(size_t)c3 * 16];
        braw[4] = (short)mx[(size_t)c4 * 16];
        braw[5] = (short)mx[(size_t)c5 * 16];
        braw[6] = (short)mx[(size_t)c6 * 16];
        braw[7] = (short)mx[(size_t)c7 * 16];

        const unsigned short* ap = urow + ba + kb;
        short8 f0 = *(const short8*)(ap);
        short8 f1 = *(const short8*)(ap + (size_t)16 * E_PAD);
        short8 f2 = *(const short8*)(ap + (size_t)32 * E_PAD);

        #define NODE_STEP(ND, A0, A1, A2)                                     \
        if (ba < rp[ND + 1] && ba + 32 > rp[ND]) {                            \
            const int klo = rp[ND] - ba, khi = rp[ND + 1] - ba;               \
            short8 bq;                                                        \
            if (klo <= 0 && khi >= 32) {                                      \
                bq = braw;                                                    \
            } else {                                                          \
                _Pragma("unroll")                                             \
                for (int j = 0; j < 8; ++j)                                   \
                    bq[j] = (kb + j >= klo && kb + j < khi) ? braw[j] : (short)0; \
            }                                                                 \
            A0 = __builtin_amdgcn_mfma_f32_16x16x32_bf16(f0, bq, A0, 0, 0, 0);\
            A1 = __builtin_amdgcn_mfma_f32_16x16x32_bf16(f1, bq, A1, 0, 0, 0);\
            A2 = __builtin_amdgcn_mfma_f32_16x16x32_bf16(f2, bq, A2, 0, 0, 0);\
        }
        NODE_STEP(0, a00, a01, a02)
        NODE_STEP(1, a10, a11, a12)
        NODE_STEP(2, a20, a21, a22)
        NODE_STEP(3, a30, a31, a32)
        #undef NODE_STEP
    }

    #define NODE_STORE(ND, A0, A1, A2)                                        \
    {                                                                         \
        unsigned short* tp = &tile[4 * w + ND][0];                            \
        _Pragma("unroll")                                                     \
        for (int i = 0; i < 4; ++i) {                                         \
            int p = g * 4 + i;                                                \
            tp[(p >> 2) * 64 + (p & 3) * 16 + x] = f2bf(A0[i]);               \
        }                                                                     \
        _Pragma("unroll")                                                     \
        for (int i = 0; i < 4; ++i) {                                         \
            int p = 16 + g * 4 + i;                                           \
            tp[(p >> 2) * 64 + (p & 3) * 16 + x] = f2bf(A1[i]);               \
        }                                                                     \
        if (g < 2) {                                                          \
            _Pragma("unroll")                                                 \
            for (int i = 0; i < 4; ++i) {                                     \
                int p = 32 + g * 4 + i;                                       \
                tp[(p >> 2) * 64 + (p & 3) * 16 + x] = f2bf(A2[i]);           \
            }                                                                 \
        }                                                                     \
        if (lane < SUB)      tp[640 + lane] = si16[(size_t)(base + ND) * SUB + lane]; \
        else if (lane < 32)  tp[640 + lane] = 0;                              \
    }
    NODE_STORE(0, a00, a01, a02)
    NODE_STORE(1, a10, a11, a12)
    NODE_STORE(2, a20, a21, a22)
    NODE_STORE(3, a30, a31, a32)
    #undef NODE_STORE
    __syncthreads();

    // ---- Phase B: MFMA MLP (A-frags from LDS tile) ----
    const int r = x;
    const short* Bp = w0f + ((size_t)l * NKK * 256 + w * 64 + lane) * 8;
    float bv = b0[l * HD + w * 16 + r];
    float4v accA = {bv, bv, bv, bv};
    float4v accB = {0.f, 0.f, 0.f, 0.f};
    #pragma unroll 5
    for (int kk = 0; kk < 20; kk += 2) {
        short8 aA = *(const short8*)((const short*)&tile[r][kk * 32 + g * 8]);
        short8 bA = *(const short8*)(Bp + (size_t)kk * 2048);
        accA = __builtin_amdgcn_mfma_f32_16x16x32_bf16(aA, bA, accA, 0, 0, 0);
        short8 aB = *(const short8*)((const short*)&tile[r][(kk + 1) * 32 + g * 8]);
        short8 bB = *(const short8*)(Bp + (size_t)(kk + 1) * 2048);
        accB = __builtin_amdgcn_mfma_f32_16x16x32_bf16(aB, bB, accB, 0, 0, 0);
    }
    {
        short8 a = *(const short8*)((const short*)&tile[r][20 * 32 + g * 8]);
        short8 b = *(const short8*)(Bp + (size_t)20 * 2048);
        accA = __builtin_amdgcn_mfma_f32_16x16x32_bf16(a, b, accA, 0, 0, 0);
    }
    __syncthreads();   // all tile reads done before h1 overlays it
    #pragma unroll
    for (int i = 0; i < 4; ++i)
        h1[g * 4 + i][w * 16 + r] = f2bf(ssp(accA[i] + accB[i]));
    __syncthreads();

    // fc1
    bv = b1[l * HD + w * 16 + r];
    float4v acc1v = {bv, bv, bv, bv};
    #pragma unroll
    for (int kk = 0; kk < 2; ++kk) {
        short8 a = *(const short8*)((const short*)&h1[r][kk * 32 + g * 8]);
        short8 b = *(const short8*)(w1f + ((size_t)(l * 2 + kk) * 256 + w * 64 + lane) * 8);
        acc1v = __builtin_amdgcn_mfma_f32_16x16x32_bf16(a, b, acc1v, 0, 0, 0);
    }
    #pragma unroll
    for (int i = 0; i < 4; ++i)
        h2[g * 4 + i][w * 16 + r] = f2bf(ssp(acc1v[i]));   // h2 disjoint from h1
    __syncthreads();

    // fc2 + residual; stage fresh xi rows for the h epilogue
    bv = b2[l * DIM + w * 16 + r];
    float4v acc2v = {bv, bv, bv, bv};
    #pragma unroll
    for (int kk = 0; kk < 2; ++kk) {
        short8 a = *(const short8*)((const short*)&h2[r][kk * 32 + g * 8]);
        short8 b = *(const short8*)(w2f + ((size_t)(l * 2 + kk) * 256 + w * 64 + lane) * 8);
        acc2v = __builtin_amdgcn_mfma_f32_16x16x32_bf16(a, b, acc2v, 0, 0, 0);
    }
    #pragma unroll
    for (int i = 0; i < 4; ++i) {
        size_t idx = (size_t)(n0 + g * 4 + i) * DIM + w * 16 + r;
        float nv = xi[idx] + acc2v[i];
        xi[idx] = nv;
        xi_s[g * 4 + i][w * 16 + r] = nv;   // xi_s disjoint from h2
    }

    // h(l+1) epilogue via MFMA: h = bf16(xi) @ bf16(Wsm[l+1]) + b (fp32 accum).
    // Waves 0,1 handle col-tiles si (cols 0..15) / mi (cols 16..31).
    if (l + 1 < LAYERS) {
        __syncthreads();
        if (w < 2) {
            const float* bs = bsm + (l + 1) * 2 * SUB;
            float bv2 = bs[w * 16 + x];
            float4v hacc = {bv2, bv2, bv2, bv2};
            #pragma unroll
            for (int kk = 0; kk < 2; ++kk) {
                short8 af;
                #pragma unroll
                for (int j = 0; j < 8; ++j)
                    af[j] = (short)f2bf(xi_s[x][kk * 32 + g * 8 + j]);
                short8 bf = *(const short8*)(wsmf +
                    ((((size_t)(l + 1) * 2 + kk) * 2 + w) * 64 + lane) * 8);
                hacc = __builtin_amdgcn_mfma_f32_16x16x32_bf16(af, bf, hacc, 0, 0, 0);
            }
            #pragma unroll
            for (int i = 0; i < 4; ++i) {
                int n = n0 + g * 4 + i;
                unsigned short v = f2bf(hacc[i]);
                if (w == 0) si16[(size_t)n * SUB + x] = v;
                else        mi_wr[(size_t)n * SUB + x] = v;
            }
        }
    }
}

extern "C" void kernel_launch(void* const* d_in, const int* in_sizes, int n_in,
                              void* d_out, int out_size, void* d_ws, size_t ws_size,
                              hipStream_t stream) {
    const int*   species = (const int*)  d_in[0];
    const int*   esrc    = (const int*)  d_in[1];
    const int*   edst    = (const int*)  d_in[2];
    const float* dist    = (const float*)d_in[3];
    const float* sw      = (const float*)d_in[4];
    const float* bo      = (const float*)d_in[5];
    const float* Wsp     = (const float*)d_in[6];
    const float* Wsm     = (const float*)d_in[7];
    const float* bsm     = (const float*)d_in[8];
    const float* w0      = (const float*)d_in[9];
    const float* b0      = (const float*)d_in[10];
    const float* w1      = (const float*)d_in[11];
    const float* b1      = (const float*)d_in[12];
    const float* w2      = (const float*)d_in[13];
    const float* b2      = (const float*)d_in[14];

    float* xi = (float*)d_out;   // N x 64 fp32, updated in place

    // ws layout: uT 48*E_PAD ush | mi16 2 x N*16 ush | si16 N*16 ush |
    //            w0f | w1f | w2f | wsmf | rowptr
    unsigned short* uT    = (unsigned short*)d_ws;
    unsigned short* mi0   = uT + (size_t)48 * E_PAD;
    unsigned short* mi1   = mi0 + (size_t)N_NODES * SUB;
    unsigned short* si16  = mi1 + (size_t)N_NODES * SUB;
    short* w0f  = (short*)(si16 + (size_t)N_NODES * SUB);
    short* w1f  = w0f + (size_t)LAYERS * NKK * 2048;
    short* w2f  = w1f + (size_t)LAYERS * 2 * 2048;
    short* wsmf = w2f + (size_t)LAYERS * 2 * 2048;
    int* rowptr = (int*)(wsmf + (size_t)LAYERS * 2 * 2 * 512);

    k_setup<<<B_ROWPTR + B_PACKW + B_PACKSM + B_U + B_INIT, 256, 0, stream>>>(
        esrc, rowptr, w0, w1, w2, w0f, w1f, w2f, Wsm, wsmf,
        dist, sw, bo, uT, species, Wsp, bsm, xi, si16, mi0);

    for (int l = 0; l < LAYERS; ++l) {
        unsigned short* mi_rd = (l & 1) ? mi1 : mi0;
        unsigned short* mi_wr = (l & 1) ? mi0 : mi1;
        k_layer<<<N_NODES / 16, 256, 0, stream>>>(rowptr, edst, uT, mi_rd, mi_wr,
                                                  si16, w0f, b0, w1f, b1, w2f, b2,
                                                  wsmf, bsm, xi, l);
    }
}

// Round 16
// 93.130 us; speedup vs baseline: 1.6668x; 1.0473x over previous
//
#include <hip/hip_runtime.h>
#include <math.h>

#define N_NODES 20000
#define N_EDGES 320000
#define NCHUNK (N_EDGES / 32)      // 10000
#define CH_STRIDE 1536             // 48 p-rows * 32 edges (ush) per chunk
#define DIM 64
#define SUB 16
#define NRBF 8
#define NB 5
#define LAYERS 3
#define FCIN (NRBF*SUB*NB + SUB)   // 656
#define KPAD 672                   // 21 * 32
#define NKK 21
#define HD 64
#define CUTOFF 5.0f
#define TS 680                     // LDS cat-tile row stride (ush): 2-way banks

// k_setup block-range sizes
#define B_ROWPTR 79                // ceil(20001/256)
#define B_PACKW  600               // (129024 + 24576) / 256
#define B_PACKSM 24                // 6144 / 256
#define B_U      1250              // N_EDGES / 256
#define B_INIT   2500              // N_NODES / 8

typedef __attribute__((ext_vector_type(8))) short short8;
typedef __attribute__((ext_vector_type(4))) float float4v;

__device__ __forceinline__ float ssp(float x) {
    float sp = fmaxf(x, 0.0f) + log1pf(expf(-fabsf(x)));
    return sp - 0.69314718055994530942f;
}

__device__ __forceinline__ unsigned short f2bf(float x) {
    unsigned int u = __float_as_uint(x);
    unsigned int r = (u + 0x7FFFu + ((u >> 16) & 1u)) >> 16;
    return (unsigned short)r;
}

// --- single setup kernel: rowptr | packw | pack Wsm | uTi | init ------------
__global__ __launch_bounds__(256) void k_setup(
    const int* __restrict__ esrc, int* __restrict__ rowptr,
    const float* __restrict__ w0, const float* __restrict__ w1,
    const float* __restrict__ w2,
    short* __restrict__ w0f, short* __restrict__ w1f, short* __restrict__ w2f,
    const float* __restrict__ Wsm, short* __restrict__ wsmf,
    const float* __restrict__ dist, const float* __restrict__ sw,
    const float* __restrict__ bo, unsigned short* __restrict__ uTi,
    const int* __restrict__ species, const float* __restrict__ Wsp,
    const float* __restrict__ bsm, float* __restrict__ xi,
    unsigned short* __restrict__ si16, unsigned short* __restrict__ mi16)
{
    __shared__ float xs[8][64];
    const unsigned bid = blockIdx.x;

    if (bid < B_ROWPTR) {                       // ---- rowptr ----
        int n = bid * 256 + threadIdx.x;
        if (n > N_NODES) return;
        int a = 0, b = N_EDGES;
        while (a < b) { int m = (a + b) >> 1; if (esrc[m] < n) a = m + 1; else b = m; }
        rowptr[n] = a;
        return;
    }
    if (bid < B_ROWPTR + B_PACKW) {             // ---- pack w0/w1/w2 ----
        const int SZ0 = LAYERS * NKK * 4 * 64 * 8;
        const int SZ12 = LAYERS * 2 * 4 * 64 * 8;
        int i = (bid - B_ROWPTR) * 256 + threadIdx.x;
        if (i < SZ0) {
            int j = i & 7, t = i >> 3;
            int lane = t & 63; t >>= 6;
            int nf = t & 3; t >>= 2;
            int kk = t % NKK, l = t / NKK;
            int kp = kk * 32 + (lane >> 4) * 8 + j;
            int col = nf * 16 + (lane & 15);
            float v = 0.0f;
            if (kp < FCIN) {
                int orig;
                if (kp < 640) {
                    int j10 = kp >> 6, rem = kp & 63, g = rem >> 4, s = rem & 15;
                    int p = g + 4 * j10;
                    orig = (p / 5) * 80 + s * 5 + (p - 5 * (p / 5));
                } else orig = kp;
                v = w0[((size_t)l * FCIN + orig) * HD + col];
            }
            w0f[i] = (short)f2bf(v);
            return;
        }
        i -= SZ0;
        if (i < 2 * SZ12) {
            const float* W = (i < SZ12) ? w1 : w2;
            short* Wf = (i < SZ12) ? w1f : w2f;
            int ii = (i < SZ12) ? i : i - SZ12;
            int j = ii & 7, t = ii >> 3;
            int lane = t & 63; t >>= 6;
            int nf = t & 3; t >>= 2;
            int kk = t & 1, l = t >> 1;
            int kp = kk * 32 + (lane >> 4) * 8 + j;
            int col = nf * 16 + (lane & 15);
            Wf[ii] = (short)f2bf(W[((size_t)l * HD + kp) * HD + col]);
        }
        return;
    }
    if (bid < B_ROWPTR + B_PACKW + B_PACKSM) {  // ---- pack Wsm for h-GEMM ----
        int i = (bid - B_ROWPTR - B_PACKW) * 256 + threadIdx.x;   // < 6144
        int j = i & 7, t = i >> 3;
        int lane = t & 63; t >>= 6;
        int nf = t & 1; t >>= 1;
        int kk = t & 1, l = t >> 1;
        int kp = kk * 32 + (lane >> 4) * 8 + j;
        int col = nf * 16 + (lane & 15);
        wsmf[i] = (short)f2bf(Wsm[(size_t)l * DIM * 2 * SUB + kp * 2 * SUB + col]);
        return;
    }
    if (bid < B_ROWPTR + B_PACKW + B_PACKSM + B_U) {   // ---- uTi (chunk-tiled) ----
        int e = (bid - B_ROWPTR - B_PACKW - B_PACKSM) * 256 + threadIdx.x;
        float d = dist[e];
        float s = sw[e];
        float rbv[NRBF], bov[NB];
        #pragma unroll
        for (int r = 0; r < NRBF; ++r) {
            float mu = (CUTOFF / (NRBF - 1)) * (float)r;
            float z = (d - mu) * ((float)NRBF / CUTOFF);
            rbv[r] = s * expf(-0.5f * z * z);
        }
        #pragma unroll
        for (int b = 0; b < NB; ++b) bov[b] = bo[e * NB + b];
        unsigned short* out = uTi + (size_t)(e >> 5) * CH_STRIDE + (e & 31);
        #pragma unroll
        for (int p = 0; p < 48; ++p) {
            float v = (p < 40) ? rbv[p / 5] * bov[p % 5] : 0.0f;
            out[p * 32] = f2bf(v);
        }
        return;
    }
    {                                            // ---- init xi + h(0) ----
        int blk = bid - (B_ROWPTR + B_PACKW + B_PACKSM + B_U);
        const int nl = threadIdx.x >> 5, j = threadIdx.x & 31;
        const int n = blk * 8 + nl;
        const int sp = species[n];
        float v0 = Wsp[sp * DIM + j];
        float v1 = Wsp[sp * DIM + 32 + j];
        xi[(size_t)n * DIM + j] = v0;
        xi[(size_t)n * DIM + 32 + j] = v1;
        xs[nl][j] = v0;
        xs[nl][32 + j] = v1;
        __syncthreads();
        float v = bsm[j];
        const float* xr = &xs[nl][0];
        #pragma unroll 8
        for (int d = 0; d < DIM; ++d) v = fmaf(xr[d], Wsm[d * 2 * SUB + j], v);
        if (j < SUB) si16[(size_t)n * SUB + j] = f2bf(v);
        else         mi16[(size_t)n * SUB + (j - SUB)] = f2bf(v);
    }
}

// --- fused per-layer kernel -------------------------------------------------
// Block = 16 nodes, 4 waves.
// Phase A: union-sweep MFMA aggregation; A-frags from chunk-tiled uTi (wave
//   reads one CONTIGUOUS 1KB block per p-tile -> 1-segment transactions).
// Phase B: fc0 (A from LDS tile) -> fc1 -> fc2 + residual -> MFMA h-epilogue.
__global__ __launch_bounds__(256) void k_layer(
    const int* __restrict__ rowptr, const int* __restrict__ edst,
    const unsigned short* __restrict__ uTi,
    const unsigned short* __restrict__ mi_rd,
    unsigned short* __restrict__ mi_wr,
    unsigned short* __restrict__ si16,
    const short* __restrict__ w0f, const float* __restrict__ b0,
    const short* __restrict__ w1f, const float* __restrict__ b1,
    const short* __restrict__ w2f, const float* __restrict__ b2,
    const short* __restrict__ wsmf, const float* __restrict__ bsm,
    float* __restrict__ xi, int l)
{
    __shared__ __align__(16) unsigned short tile[16][TS];    // 21760 B total LDS
    unsigned short (*h1)[72] = (unsigned short (*)[72])((char*)tile);          // 2304 B
    unsigned short (*h2)[72] = (unsigned short (*)[72])((char*)tile + 4608);   // 2304 B
    float (*xi_s)[68]        = (float (*)[68])((char*)tile + 9216);            // 4352 B

    const int lane = threadIdx.x & 63;
    const int w = threadIdx.x >> 6;
    const int n0 = blockIdx.x * 16;
    const int x = lane & 15, g = lane >> 4;

    // ---- Phase A: union-sweep MFMA aggregation into LDS tile ----
    const unsigned short* mx = mi_rd + x;
    const int base = n0 + 4 * w;
    int rp[5];
    #pragma unroll
    for (int i = 0; i < 5; ++i) rp[i] = rowptr[base + i];

    float4v a00={0,0,0,0}, a01={0,0,0,0}, a02={0,0,0,0};
    float4v a10={0,0,0,0}, a11={0,0,0,0}, a12={0,0,0,0};
    float4v a20={0,0,0,0}, a21={0,0,0,0}, a22={0,0,0,0};
    float4v a30={0,0,0,0}, a31={0,0,0,0}, a32={0,0,0,0};

    const int kb = g * 8;
    for (int ba = rp[0] & ~31; ba < rp[4]; ba += 32) {
        // shared loads for this chunk (once per chunk, all 4 nodes)
        int4 i0 = *(const int4*)(edst + ba + kb);
        int4 i1 = *(const int4*)(edst + ba + kb + 4);
        // all edst entries are valid node indices (chunk within [0,N_EDGES))
        short8 braw;
        braw[0] = (short)mx[(size_t)i0.x * 16];
        braw[1] = (short)mx[(size_t)i0.y * 16];
        braw[2] = (short)mx[(size_t)i0.z * 16];
        braw[3] = (short)mx[(size_t)i0.w * 16];
        braw[4] = (short)mx[(size_t)i1.x * 16];
        braw[5] = (short)mx[(size_t)i1.y * 16];
        braw[6] = (short)mx[(size_t)i1.z * 16];
        braw[7] = (short)mx[(size_t)i1.w * 16];

        // A-frags: contiguous 1KB per p-tile across the wave
        const unsigned short* ap = uTi + (size_t)(ba >> 5) * CH_STRIDE + x * 32 + kb;
        short8 f0 = *(const short8*)(ap);
        short8 f1 = *(const short8*)(ap + 512);
        short8 f2 = *(const short8*)(ap + 1024);

        #define NODE_STEP(ND, A0, A1, A2)                                     \
        if (ba < rp[ND + 1] && ba + 32 > rp[ND]) {                            \
            const int klo = rp[ND] - ba, khi = rp[ND + 1] - ba;               \
            short8 bq;                                                        \
            if (klo <= 0 && khi >= 32) {                                      \
                bq = braw;                                                    \
            } else {                                                          \
                _Pragma("unroll")                                             \
                for (int j = 0; j < 8; ++j)                                   \
                    bq[j] = (kb + j >= klo && kb + j < khi) ? braw[j] : (short)0; \
            }                                                                 \
            A0 = __builtin_amdgcn_mfma_f32_16x16x32_bf16(f0, bq, A0, 0, 0, 0);\
            A1 = __builtin_amdgcn_mfma_f32_16x16x32_bf16(f1, bq, A1, 0, 0, 0);\
            A2 = __builtin_amdgcn_mfma_f32_16x16x32_bf16(f2, bq, A2, 0, 0, 0);\
        }
        NODE_STEP(0, a00, a01, a02)
        NODE_STEP(1, a10, a11, a12)
        NODE_STEP(2, a20, a21, a22)
        NODE_STEP(3, a30, a31, a32)
        #undef NODE_STEP
    }

    #define NODE_STORE(ND, A0, A1, A2)                                        \
    {                                                                         \
        unsigned short* tp = &tile[4 * w + ND][0];                            \
        _Pragma("unroll")                                                     \
        for (int i = 0; i < 4; ++i) {                                         \
            int p = g * 4 + i;                                                \
            tp[(p >> 2) * 64 + (p & 3) * 16 + x] = f2bf(A0[i]);               \
        }                                                                     \
        _Pragma("unroll")                                                     \
        for (int i = 0; i < 4; ++i) {                                         \
            int p = 16 + g * 4 + i;                                           \
            tp[(p >> 2) * 64 + (p & 3) * 16 + x] = f2bf(A1[i]);               \
        }                                                                     \
        if (g < 2) {                                                          \
            _Pragma("unroll")                                                 \
            for (int i = 0; i < 4; ++i) {                                     \
                int p = 32 + g * 4 + i;                                       \
                tp[(p >> 2) * 64 + (p & 3) * 16 + x] = f2bf(A2[i]);           \
            }                                                                 \
        }                                                                     \
        if (lane < SUB)      tp[640 + lane] = si16[(size_t)(base + ND) * SUB + lane]; \
        else if (lane < 32)  tp[640 + lane] = 0;                              \
    }
    NODE_STORE(0, a00, a01, a02)
    NODE_STORE(1, a10, a11, a12)
    NODE_STORE(2, a20, a21, a22)
    NODE_STORE(3, a30, a31, a32)
    #undef NODE_STORE
    __syncthreads();

    // ---- Phase B: MFMA MLP (A-frags from LDS tile) ----
    const int r = x;
    const short* Bp = w0f + ((size_t)l * NKK * 256 + w * 64 + lane) * 8;
    float bv = b0[l * HD + w * 16 + r];
    float4v accA = {bv, bv, bv, bv};
    float4v accB = {0.f, 0.f, 0.f, 0.f};
    #pragma unroll 5
    for (int kk = 0; kk < 20; kk += 2) {
        short8 aA = *(const short8*)((const short*)&tile[r][kk * 32 + g * 8]);
        short8 bA = *(const short8*)(Bp + (size_t)kk * 2048);
        accA = __builtin_amdgcn_mfma_f32_16x16x32_bf16(aA, bA, accA, 0, 0, 0);
        short8 aB = *(const short8*)((const short*)&tile[r][(kk + 1) * 32 + g * 8]);
        short8 bB = *(const short8*)(Bp + (size_t)(kk + 1) * 2048);
        accB = __builtin_amdgcn_mfma_f32_16x16x32_bf16(aB, bB, accB, 0, 0, 0);
    }
    {
        short8 a = *(const short8*)((const short*)&tile[r][20 * 32 + g * 8]);
        short8 b = *(const short8*)(Bp + (size_t)20 * 2048);
        accA = __builtin_amdgcn_mfma_f32_16x16x32_bf16(a, b, accA, 0, 0, 0);
    }
    __syncthreads();   // all tile reads done before h1 overlays it
    #pragma unroll
    for (int i = 0; i < 4; ++i)
        h1[g * 4 + i][w * 16 + r] = f2bf(ssp(accA[i] + accB[i]));
    __syncthreads();

    // fc1
    bv = b1[l * HD + w * 16 + r];
    float4v acc1v = {bv, bv, bv, bv};
    #pragma unroll
    for (int kk = 0; kk < 2; ++kk) {
        short8 a = *(const short8*)((const short*)&h1[r][kk * 32 + g * 8]);
        short8 b = *(const short8*)(w1f + ((size_t)(l * 2 + kk) * 256 + w * 64 + lane) * 8);
        acc1v = __builtin_amdgcn_mfma_f32_16x16x32_bf16(a, b, acc1v, 0, 0, 0);
    }
    #pragma unroll
    for (int i = 0; i < 4; ++i)
        h2[g * 4 + i][w * 16 + r] = f2bf(ssp(acc1v[i]));   // h2 disjoint from h1
    __syncthreads();

    // fc2 + residual; stage fresh xi rows for the h epilogue
    bv = b2[l * DIM + w * 16 + r];
    float4v acc2v = {bv, bv, bv, bv};
    #pragma unroll
    for (int kk = 0; kk < 2; ++kk) {
        short8 a = *(const short8*)((const short*)&h2[r][kk * 32 + g * 8]);
        short8 b = *(const short8*)(w2f + ((size_t)(l * 2 + kk) * 256 + w * 64 + lane) * 8);
        acc2v = __builtin_amdgcn_mfma_f32_16x16x32_bf16(a, b, acc2v, 0, 0, 0);
    }
    #pragma unroll
    for (int i = 0; i < 4; ++i) {
        size_t idx = (size_t)(n0 + g * 4 + i) * DIM + w * 16 + r;
        float nv = xi[idx] + acc2v[i];
        xi[idx] = nv;
        xi_s[g * 4 + i][w * 16 + r] = nv;   // xi_s disjoint from h2
    }

    // h(l+1) epilogue via MFMA: h = bf16(xi) @ bf16(Wsm[l+1]) + b (fp32 accum).
    if (l + 1 < LAYERS) {
        __syncthreads();
        if (w < 2) {
            const float* bs = bsm + (l + 1) * 2 * SUB;
            float bv2 = bs[w * 16 + x];
            float4v hacc = {bv2, bv2, bv2, bv2};
            #pragma unroll
            for (int kk = 0; kk < 2; ++kk) {
                short8 af;
                #pragma unroll
                for (int j = 0; j < 8; ++j)
                    af[j] = (short)f2bf(xi_s[x][kk * 32 + g * 8 + j]);
                short8 bf = *(const short8*)(wsmf +
                    ((((size_t)(l + 1) * 2 + kk) * 2 + w) * 64 + lane) * 8);
                hacc = __builtin_amdgcn_mfma_f32_16x16x32_bf16(af, bf, hacc, 0, 0, 0);
            }
            #pragma unroll
            for (int i = 0; i < 4; ++i) {
                int n = n0 + g * 4 + i;
                unsigned short v = f2bf(hacc[i]);
                if (w == 0) si16[(size_t)n * SUB + x] = v;
                else        mi_wr[(size_t)n * SUB + x] = v;
            }
        }
    }
}

extern "C" void kernel_launch(void* const* d_in, const int* in_sizes, int n_in,
                              void* d_out, int out_size, void* d_ws, size_t ws_size,
                              hipStream_t stream) {
    const int*   species = (const int*)  d_in[0];
    const int*   esrc    = (const int*)  d_in[1];
    const int*   edst    = (const int*)  d_in[2];
    const float* dist    = (const float*)d_in[3];
    const float* sw      = (const float*)d_in[4];
    const float* bo      = (const float*)d_in[5];
    const float* Wsp     = (const float*)d_in[6];
    const float* Wsm     = (const float*)d_in[7];
    const float* bsm     = (const float*)d_in[8];
    const float* w0      = (const float*)d_in[9];
    const float* b0      = (const float*)d_in[10];
    const float* w1      = (const float*)d_in[11];
    const float* b1      = (const float*)d_in[12];
    const float* w2      = (const float*)d_in[13];
    const float* b2      = (const float*)d_in[14];

    float* xi = (float*)d_out;   // N x 64 fp32, updated in place

    // ws layout: uTi NCHUNK*1536 ush | mi16 2 x N*16 ush | si16 N*16 ush |
    //            w0f | w1f | w2f | wsmf | rowptr
    unsigned short* uTi   = (unsigned short*)d_ws;
    unsigned short* mi0   = uTi + (size_t)NCHUNK * CH_STRIDE;
    unsigned short* mi1   = mi0 + (size_t)N_NODES * SUB;
    unsigned short* si16  = mi1 + (size_t)N_NODES * SUB;
    short* w0f  = (short*)(si16 + (size_t)N_NODES * SUB);
    short* w1f  = w0f + (size_t)LAYERS * NKK * 2048;
    short* w2f  = w1f + (size_t)LAYERS * 2 * 2048;
    short* wsmf = w2f + (size_t)LAYERS * 2 * 2048;
    int* rowptr = (int*)(wsmf + (size_t)LAYERS * 2 * 2 * 512);

    k_setup<<<B_ROWPTR + B_PACKW + B_PACKSM + B_U + B_INIT, 256, 0, stream>>>(
        esrc, rowptr, w0, w1, w2, w0f, w1f, w2f, Wsm, wsmf,
        dist, sw, bo, uTi, species, Wsp, bsm, xi, si16, mi0);

    for (int l = 0; l < LAYERS; ++l) {
        unsigned short* mi_rd = (l & 1) ? mi1 : mi0;
        unsigned short* mi_wr = (l & 1) ? mi0 : mi1;
        k_layer<<<N_NODES / 16, 256, 0, stream>>>(rowptr, edst, uTi, mi_rd, mi_wr,
                                                  si16, w0f, b0, w1f, b1, w2f, b2,
                                                  wsmf, bsm, xi, l);
    }
}